// Round 15
// baseline (230.453 us; speedup 1.0000x reference)
//
#include <hip/hip_runtime.h>

#define TT 128

// LIF constants
#define DECAY_U 0.75f
#define DECAY_V 0.96875f
#define THETA   5120.0f
#define POOLW   88.0f

__device__ __forceinline__ void lif_step(float xt, float& u, float& v, int& refc, float& s) {
    u = __fadd_rn(__fmul_rn(u, DECAY_U), __fmul_rn(xt, 64.0f));
    float vn = __fadd_rn(__fmul_rn(v, DECAY_V), u);
    v = refc ? 0.0f : vn;
    s = (v >= THETA) ? 1.0f : 0.0f;
    if (s > 0.f) { refc = 1; v = 0.f; }
    else         { refc = refc > 0 ? refc - 1 : 0; }
}

// Serial LIF over an LDS column: col[t*stride], t=0..127.
__device__ __forceinline__ void lif_seq_lds(float* col, int stride) {
    float u = 0.f, v = 0.f;
    int refc = 0;
    #pragma unroll 16
    for (int t = 0; t < TT; ++t) {
        float s;
        lif_step(col[t * stride], u, v, refc, s);
        col[t * stride] = s;
    }
}

// ---------------- Weight reorder ----------------
// wT1: [ky][kx*2+c][oc16]  800 floats  |  wT2: [tap][c][oc32]  4608 floats
__global__ void wtrans_k(const float* __restrict__ w1, const float* __restrict__ w2,
                         float* __restrict__ wT1, float* __restrict__ wT2) {
    int i = blockIdx.x * 256 + threadIdx.x;
    if (i < 800) {
        int oc = i & 15;
        int r2 = i >> 4;            // ky*10 + (kx*2+c)
        int ky = r2 / 10;
        int rr = r2 - ky * 10;
        int kx = rr >> 1, c = rr & 1;
        wT1[i] = w1[oc*50 + c*25 + ky*5 + kx];
    }
    if (i < 4608) {
        int oc = i & 31;
        int c  = (i >> 5) & 15;
        int tap = i >> 9;
        wT2[i] = w2[oc*144 + c*9 + tap];
    }
}

// ---------------- L1: sum_pool(x,4)*88 + LIF + pack -> pk1 u8 ----------------
__global__ void pool1_lif_k(const float* __restrict__ x, unsigned char* __restrict__ pk1) {
    __shared__ float sb[TT][3];
    int t = threadIdx.x & 127, c = threadIdx.x >> 7;
    int pos = blockIdx.x & 1023, b = blockIdx.x >> 10;
    int px = pos & 31, py = pos >> 5;
    const float* base = x + (size_t)((((b*2 + c)*128 + py*4)*128) + px*4) * 128 + t;
    float s = 0.f;
    #pragma unroll
    for (int dy = 0; dy < 4; ++dy)
        #pragma unroll
        for (int dx = 0; dx < 4; ++dx)
            s += base[(dy*128 + dx) * 128];
    sb[t][c] = s * POOLW;
    __syncthreads();
    if (threadIdx.x < 2) lif_seq_lds(&sb[0][threadIdx.x], 3);
    __syncthreads();
    if (threadIdx.x < 128) {
        unsigned int v = (sb[t][0] > 0.5f ? 1u : 0u) | (sb[t][1] > 0.5f ? 2u : 0u);
        pk1[(size_t)b * 131072 + (size_t)pos * 128 + t] = (unsigned char)v;
    }
}

// ---------------- L2: conv1 single-stage GEMM (2 pos/block) + LIF + pack ----------
// 256 thr: og=tid>>6 (4 oc), pos=(tid>>5)&1, tg=tid&31 (4 t). K=50 staged once.
// Rolled ky loop + explicit 1-deep prefetch of wv/xw.
__global__ __launch_bounds__(256) void conv1_gemm_k(const unsigned char* __restrict__ pk1,
                                                    const float* __restrict__ wT1,
                                                    unsigned short* __restrict__ pk2) {
    __shared__ float smem[4760];            // WS[800] | XN[5*6*132=3960] ; sb[128*33=4224] aliases
    float* WS = smem;
    unsigned int* XN = (unsigned int*)(smem + 800);
    float* sb = smem;
    int tid = threadIdx.x;
    int ppair = blockIdx.x & 511, b = blockIdx.x >> 9;
    int py = ppair >> 4, px0 = (ppair & 15) * 2;
    const unsigned char* pp = pk1 + (size_t)b * 131072;

    #pragma unroll
    for (int i = 0; i < 4; ++i) {
        int e = tid + 256*i;
        if (e < 800) WS[e] = wT1[e];
    }
    #pragma unroll
    for (int i = 0; i < 15; ++i) {
        int e = tid + 256*i;                 // 3840 entries
        int row = e >> 7, t = e & 127;
        int ky = row / 6, xc = row - ky*6;
        int iy = py + ky - 2, ix = px0 + xc - 2;
        bool vs = ((unsigned)iy < 32u) && ((unsigned)ix < 32u) && (t > 0);
        XN[row*132 + t] = vs ? (unsigned int)pp[(iy*32 + ix)*128 + t - 1] : 0u;
    }
    __syncthreads();

    int tg = tid & 31;
    int pos = (tid >> 5) & 1;
    int og = tid >> 6;                       // wave-uniform
    float acc[4][4];
    #pragma unroll
    for (int i = 0; i < 4; ++i)
        #pragma unroll
        for (int j = 0; j < 4; ++j) acc[i][j] = 0.f;

    uint4  xw = *(const uint4*)&XN[pos*132 + tg*4];          // (ky0,kx0)
    float4 wv = *(const float4*)&WS[og*4];                   // (ky0,kx0,c0)
    #pragma unroll 1
    for (int ky = 0; ky < 5; ++ky) {
        #pragma unroll
        for (int kx = 0; kx < 5; ++kx) {
            int nkx = (kx == 4) ? 0 : kx + 1;
            int nky = (kx == 4) ? ky + 1 : ky;
            uint4 xw_n = (nky < 5) ? *(const uint4*)&XN[(nky*6 + nkx + pos)*132 + tg*4] : xw;
            #pragma unroll
            for (int c = 0; c < 2; ++c) {
                float4 wv_n;
                if (c == 0)       wv_n = *(const float4*)&WS[(ky*10 + kx*2 + 1)*16 + og*4];
                else if (nky < 5) wv_n = *(const float4*)&WS[(nky*10 + nkx*2)*16 + og*4];
                else              wv_n = wv;
                float x0 = (float)((xw.x >> c) & 1u);
                float x1 = (float)((xw.y >> c) & 1u);
                float x2 = (float)((xw.z >> c) & 1u);
                float x3 = (float)((xw.w >> c) & 1u);
                acc[0][0] = fmaf(wv.x, x0, acc[0][0]);
                acc[0][1] = fmaf(wv.x, x1, acc[0][1]);
                acc[0][2] = fmaf(wv.x, x2, acc[0][2]);
                acc[0][3] = fmaf(wv.x, x3, acc[0][3]);
                acc[1][0] = fmaf(wv.y, x0, acc[1][0]);
                acc[1][1] = fmaf(wv.y, x1, acc[1][1]);
                acc[1][2] = fmaf(wv.y, x2, acc[1][2]);
                acc[1][3] = fmaf(wv.y, x3, acc[1][3]);
                acc[2][0] = fmaf(wv.z, x0, acc[2][0]);
                acc[2][1] = fmaf(wv.z, x1, acc[2][1]);
                acc[2][2] = fmaf(wv.z, x2, acc[2][2]);
                acc[2][3] = fmaf(wv.z, x3, acc[2][3]);
                acc[3][0] = fmaf(wv.w, x0, acc[3][0]);
                acc[3][1] = fmaf(wv.w, x1, acc[3][1]);
                acc[3][2] = fmaf(wv.w, x2, acc[3][2]);
                acc[3][3] = fmaf(wv.w, x3, acc[3][3]);
                wv = wv_n;
            }
            xw = xw_n;
        }
    }
    __syncthreads();   // XN/WS reads done; reuse smem as sb
    // sb[t][col], col = oc*2 + pos (32 cols, stride 33)
    #pragma unroll
    for (int i = 0; i < 4; ++i)
        #pragma unroll
        for (int j = 0; j < 4; ++j)
            sb[(tg*4 + j)*33 + (og*4 + i)*2 + pos] = acc[i][j];
    __syncthreads();
    if (tid < 32) lif_seq_lds(&sb[tid], 33);
    __syncthreads();
    if (tid < 128) {
        int t = tid;
        #pragma unroll
        for (int p2 = 0; p2 < 2; ++p2) {
            unsigned int w = 0;
            #pragma unroll
            for (int oc = 0; oc < 16; ++oc)
                w |= (sb[t*33 + oc*2 + p2] > 0.5f ? 1u : 0u) << oc;
            int pos_out = py*32 + px0 + p2;
            pk2[(size_t)b * 131072 + (size_t)pos_out * 128 + t] = (unsigned short)w;
        }
    }
}

// ---------------- L3: sum_pool(2)*88 (delayed, packed in) + LIF + pack -> pk3 -----
__global__ __launch_bounds__(256) void pool2pack_k(const unsigned short* __restrict__ pk2,
                                                   unsigned short* __restrict__ pk3) {
    __shared__ float sb[TT][17];
    int tid = threadIdx.x;
    int t = tid & 127, half = tid >> 7;
    int pos = blockIdx.x & 255, b = blockIdx.x >> 8;
    int px = pos & 15, py = pos >> 4;
    unsigned int w0 = 0, w1 = 0, w2 = 0, w3 = 0;
    if (t > 0) {
        const unsigned short* q = pk2 + (size_t)b * 131072 + (size_t)(py*2*32 + px*2) * 128 + (t - 1);
        w0 = q[0]; w1 = q[128]; w2 = q[32*128]; w3 = q[33*128];
    }
    #pragma unroll
    for (int j = 0; j < 8; ++j) {
        int c = half*8 + j;
        int cnt = ((w0 >> c) & 1) + ((w1 >> c) & 1) + ((w2 >> c) & 1) + ((w3 >> c) & 1);
        sb[t][c] = POOLW * (float)cnt;
    }
    __syncthreads();
    if (tid < 16) lif_seq_lds(&sb[0][tid], 17);
    __syncthreads();
    if (tid < 128) {
        unsigned int w = 0;
        #pragma unroll
        for (int c = 0; c < 16; ++c)
            w |= (sb[tid][c] > 0.5f ? 1u : 0u) << c;
        pk3[(size_t)b * 32768 + (size_t)pos * 128 + tid] = (unsigned short)w;
    }
}

// ---------------- L4: conv2 single-stage GEMM + LIF + pack -> pk4 ----------------
// 256 thr: og=tid>>5 (4 oc of 32), tg=tid&31 (4 t). K=144 staged once (packed X).
// Rolled tap loop + explicit 1-deep prefetch of wv/xw.
__global__ __launch_bounds__(256) void conv2_gemm_k(const unsigned short* __restrict__ pk3,
                                                    const float* __restrict__ wT2,
                                                    unsigned int* __restrict__ pk4) {
    __shared__ float smem[5796];            // WS[4608] | XL[9*132=1188] ; sb[128*33] aliases
    float* WS = smem;
    unsigned int* XL = (unsigned int*)(smem + 4608);
    float* sb = smem;
    int tid = threadIdx.x;
    int pos = blockIdx.x & 255, b = blockIdx.x >> 8;
    int px = pos & 15, py = pos >> 4;
    const unsigned short* pp = pk3 + (size_t)b * 32768;

    #pragma unroll
    for (int i = 0; i < 18; ++i)
        WS[tid + 256*i] = wT2[tid + 256*i];
    #pragma unroll
    for (int i = 0; i < 5; ++i) {
        int e = tid + 256*i;
        if (e < 1152) {
            int tap = e >> 7, t = e & 127;
            int ky = tap / 3, kx = tap - ky*3;
            int iy = py + ky - 1, ix = px + kx - 1;
            bool vs = ((unsigned)iy < 16u) && ((unsigned)ix < 16u) && (t > 0);
            XL[tap*132 + t] = vs ? (unsigned int)pp[(iy*16 + ix)*128 + t - 1] : 0u;
        }
    }
    __syncthreads();

    int tg = tid & 31;
    int og = tid >> 5;
    float acc[4][4];
    #pragma unroll
    for (int i = 0; i < 4; ++i)
        #pragma unroll
        for (int j = 0; j < 4; ++j) acc[i][j] = 0.f;

    uint4  xw = *(const uint4*)&XL[tg*4];
    float4 wv = *(const float4*)&WS[og*4];
    #pragma unroll 1
    for (int tap = 0; tap < 9; ++tap) {
        uint4 xw_n = (tap < 8) ? *(const uint4*)&XL[(tap+1)*132 + tg*4] : xw;
        #pragma unroll
        for (int c = 0; c < 16; ++c) {
            float4 wv_n;
            if (c < 15)        wv_n = *(const float4*)&WS[tap*512 + (c+1)*32 + og*4];
            else if (tap < 8)  wv_n = *(const float4*)&WS[(tap+1)*512 + og*4];
            else               wv_n = wv;
            float x0 = (float)((xw.x >> c) & 1u);
            float x1 = (float)((xw.y >> c) & 1u);
            float x2 = (float)((xw.z >> c) & 1u);
            float x3 = (float)((xw.w >> c) & 1u);
            acc[0][0] = fmaf(wv.x, x0, acc[0][0]);
            acc[0][1] = fmaf(wv.x, x1, acc[0][1]);
            acc[0][2] = fmaf(wv.x, x2, acc[0][2]);
            acc[0][3] = fmaf(wv.x, x3, acc[0][3]);
            acc[1][0] = fmaf(wv.y, x0, acc[1][0]);
            acc[1][1] = fmaf(wv.y, x1, acc[1][1]);
            acc[1][2] = fmaf(wv.y, x2, acc[1][2]);
            acc[1][3] = fmaf(wv.y, x3, acc[1][3]);
            acc[2][0] = fmaf(wv.z, x0, acc[2][0]);
            acc[2][1] = fmaf(wv.z, x1, acc[2][1]);
            acc[2][2] = fmaf(wv.z, x2, acc[2][2]);
            acc[2][3] = fmaf(wv.z, x3, acc[2][3]);
            acc[3][0] = fmaf(wv.w, x0, acc[3][0]);
            acc[3][1] = fmaf(wv.w, x1, acc[3][1]);
            acc[3][2] = fmaf(wv.w, x2, acc[3][2]);
            acc[3][3] = fmaf(wv.w, x3, acc[3][3]);
            wv = wv_n;
        }
        xw = xw_n;
    }
    __syncthreads();   // XL/WS reads done; reuse smem as sb
    #pragma unroll
    for (int i = 0; i < 4; ++i)
        #pragma unroll
        for (int j = 0; j < 4; ++j)
            sb[(tg*4 + j)*33 + og*4 + i] = acc[i][j];
    __syncthreads();
    if (tid < 32) lif_seq_lds(&sb[tid], 33);
    __syncthreads();
    if (tid < 128) {
        unsigned int w = 0;
        #pragma unroll
        for (int oc = 0; oc < 32; ++oc)
            w |= (sb[tid*33 + oc] > 0.5f ? 1u : 0u) << oc;
        pk4[(size_t)b * 32768 + (size_t)pos * 128 + tid] = w;
    }
}

// ---------------- L5: sum_pool(2)*88 (delayed, packed in) + LIF -> s5 fp32 --------
__global__ void pool3_lif_k(const unsigned int* __restrict__ pk4, float* __restrict__ s5) {
    __shared__ float sb[TT][3];
    int t = threadIdx.x & 127, pos = threadIdx.x >> 7;
    int n = blockIdx.x * 2 + pos;
    int px = n & 7, py = (n >> 3) & 7, c = (n >> 6) & 31, b = n >> 11;
    float acc = 0.f;
    if (t > 0) {
        const unsigned int* q = pk4 + (size_t)b * 32768 + (size_t)(py*2*16 + px*2) * 128 + (t - 1);
        unsigned int w0 = q[0], w1 = q[128], w2 = q[16*128], w3 = q[17*128];
        int cnt = ((w0 >> c) & 1) + ((w1 >> c) & 1) + ((w2 >> c) & 1) + ((w3 >> c) & 1);
        acc = POOLW * (float)cnt;
    }
    sb[t][pos] = acc;
    __syncthreads();
    if (threadIdx.x < 2) lif_seq_lds(&sb[0][threadIdx.x], 3);
    __syncthreads();
    s5[(size_t)n * TT + t] = sb[t][pos];
}

// ---------------- L6: fc1 tiled K-split GEMM ----------------
__global__ __launch_bounds__(256) void fc1_gemm_k(const float* __restrict__ s5,
                                                  const float* __restrict__ wf1,
                                                  float* __restrict__ part) {
    __shared__ float WT[64][68];
    __shared__ float ST[64][68];
    int bid = blockIdx.x;
    int kc = bid & 7;
    int ot = (bid >> 3) & 7;
    int tt = (bid >> 6) & 1;
    int b  = bid >> 7;
    int tid = threadIdx.x;
    int oo = tid >> 4;
    int to = tid & 15;

    const float* wbase = wf1 + (size_t)(ot*64) * 2048 + kc*256;
    const float* sbase = s5 + (size_t)b * 262144 + (size_t)(kc*256) * 128;

    float acc[4][4];
    #pragma unroll
    for (int i = 0; i < 4; ++i)
        #pragma unroll
        for (int j = 0; j < 4; ++j) acc[i][j] = 0.f;

    for (int ks = 0; ks < 4; ++ks) {
        __syncthreads();
        #pragma unroll
        for (int i = 0; i < 16; ++i) {
            int e = tid + 256*i;
            int o = e >> 6, f = e & 63;
            WT[f][o] = wbase[(size_t)o * 2048 + ks*64 + f];
        }
        #pragma unroll
        for (int i = 0; i < 16; ++i) {
            int e = tid + 256*i;
            int f = e >> 6, tl = e & 63;
            int tsrc = tt*64 + tl - 1;
            ST[f][tl] = (tsrc < 0) ? 0.f : sbase[(size_t)f * 128 + ks*64*128 + tsrc];
        }
        __syncthreads();
        #pragma unroll 4
        for (int k = 0; k < 64; ++k) {
            float4 a = *(const float4*)&WT[k][oo*4];
            float4 s = *(const float4*)&ST[k][to*4];
            acc[0][0] = fmaf(a.x, s.x, acc[0][0]);
            acc[0][1] = fmaf(a.x, s.y, acc[0][1]);
            acc[0][2] = fmaf(a.x, s.z, acc[0][2]);
            acc[0][3] = fmaf(a.x, s.w, acc[0][3]);
            acc[1][0] = fmaf(a.y, s.x, acc[1][0]);
            acc[1][1] = fmaf(a.y, s.y, acc[1][1]);
            acc[1][2] = fmaf(a.y, s.z, acc[1][2]);
            acc[1][3] = fmaf(a.y, s.w, acc[1][3]);
            acc[2][0] = fmaf(a.z, s.x, acc[2][0]);
            acc[2][1] = fmaf(a.z, s.y, acc[2][1]);
            acc[2][2] = fmaf(a.z, s.z, acc[2][2]);
            acc[2][3] = fmaf(a.z, s.w, acc[2][3]);
            acc[3][0] = fmaf(a.w, s.x, acc[3][0]);
            acc[3][1] = fmaf(a.w, s.y, acc[3][1]);
            acc[3][2] = fmaf(a.w, s.z, acc[3][2]);
            acc[3][3] = fmaf(a.w, s.w, acc[3][3]);
        }
    }
    float* pb = part + (size_t)kc * 524288 + (size_t)b * 65536
              + (size_t)(ot*64 + oo*4) * 128 + tt*64 + to*4;
    #pragma unroll
    for (int i = 0; i < 4; ++i)
        #pragma unroll
        for (int j = 0; j < 4; ++j)
            pb[(size_t)i * 128 + j] = acc[i][j];
}

// ---------------- L6b: sum 8 K-chunks (fixed order) + LIF -> s6 ----------------
__global__ void fc1_reduce_lif_k(const float* __restrict__ part, float* __restrict__ s6) {
    __shared__ float sb[TT][3];
    int t = threadIdx.x & 127, pos = threadIdx.x >> 7;
    int n = blockIdx.x * 2 + pos;
    float s = 0.f;
    #pragma unroll
    for (int kc = 0; kc < 8; ++kc)
        s += part[(size_t)kc * 524288 + (size_t)n * 128 + t];
    sb[t][pos] = s;
    __syncthreads();
    if (threadIdx.x < 2) lif_seq_lds(&sb[0][threadIdx.x], 3);
    __syncthreads();
    s6[(size_t)n * TT + t] = sb[t][pos];
}

// ---------------- L7: fc2 512->11 (delayed) + LIF + final shift -> out ----------
__global__ void fc2_lif_k(const float* __restrict__ s6, const float* __restrict__ wf2,
                          float* __restrict__ out) {
    __shared__ float sb[TT];
    int t = threadIdx.x;
    int o = blockIdx.x % 11, b = blockIdx.x / 11;
    float acc = 0.f;
    if (t > 0) {
        const float* sp = s6 + (size_t)b * 65536 + (t - 1);
        const float* wp = wf2 + o * 512;
        for (int f = 0; f < 512; f += 4) {
            float4 w = *(const float4*)&wp[f];
            acc = fmaf(w.x, sp[(size_t)f * 128], acc);
            acc = fmaf(w.y, sp[(size_t)(f+1) * 128], acc);
            acc = fmaf(w.z, sp[(size_t)(f+2) * 128], acc);
            acc = fmaf(w.w, sp[(size_t)(f+3) * 128], acc);
        }
    }
    sb[t] = acc;
    __syncthreads();
    if (t == 0) lif_seq_lds(sb, 1);
    __syncthreads();
    float* q = out + (size_t)(b*11 + o) * TT;
    if (t == 0) q[0] = 0.f;
    if (t < TT - 1) q[t + 1] = sb[t];
}

extern "C" void kernel_launch(void* const* d_in, const int* in_sizes, int n_in,
                              void* d_out, int out_size, void* d_ws, size_t ws_size,
                              hipStream_t stream) {
    const float* x   = (const float*)d_in[0];
    const float* w1  = (const float*)d_in[1];
    const float* w2  = (const float*)d_in[2];
    const float* wf1 = (const float*)d_in[3];
    const float* wf2 = (const float*)d_in[4];
    float* out = (float*)d_out;

    float* ws = (float*)d_ws;
    float* PART = ws;                        // 4,194,304 floats
    float* A    = PART + 4194304;            // 2,097,152 floats (s5)
    float* S6   = A + 2097152;               // 524,288 floats
    float* WT1  = S6 + 524288;               // 800 floats
    float* WT2  = WT1 + 800;                 // 4608 floats
    unsigned char*  PK1 = (unsigned char*)(WT2 + 4608);            // 1,048,576 B
    unsigned short* PK2 = (unsigned short*)(PK1 + 1048576);        // 1,048,576 u16
    unsigned short* PK3 = (unsigned short*)((char*)PK2 + 2097152); // 262,144 u16
    unsigned int*   PK4 = (unsigned int*)((char*)PK3 + 524288);    // 262,144 u32

    // weight reorder for GEMM convs
    wtrans_k<<<dim3(18), 256, 0, stream>>>(w1, w2, WT1, WT2);
    // L1: pool1+LIF+pack -> PK1
    pool1_lif_k<<<dim3(8192), 256, 0, stream>>>(x, PK1);
    // L2: conv1 single-stage GEMM +LIF+pack -> PK2 (2 pos/block, prefetched)
    conv1_gemm_k<<<dim3(4096), 256, 0, stream>>>(PK1, WT1, PK2);
    // L3: pool2+LIF+pack -> PK3
    pool2pack_k<<<dim3(2048), 256, 0, stream>>>(PK2, PK3);
    // L4: conv2 single-stage GEMM +LIF+pack -> PK4 (prefetched)
    conv2_gemm_k<<<dim3(2048), 256, 0, stream>>>(PK3, WT2, PK4);
    // L5: pool3+LIF -> A (s5)
    pool3_lif_k<<<dim3(8192), 256, 0, stream>>>(PK4, A);
    // L6: fc1 GEMM -> PART; reduce+LIF -> S6
    fc1_gemm_k      <<<dim3(1024), 256, 0, stream>>>(A, wf1, PART);
    fc1_reduce_lif_k<<<dim3(2048), 256, 0, stream>>>(PART, S6);
    // L7: fc2+LIF+shift -> d_out
    fc2_lif_k<<<dim3(88), 128, 0, stream>>>(S6, wf2, out);
}

// Round 16
// 220.291 us; speedup vs baseline: 1.0461x; 1.0461x over previous
//
#include <hip/hip_runtime.h>

#define TT 128

typedef float v2f __attribute__((ext_vector_type(2)));

// LIF constants
#define DECAY_U 0.75f
#define DECAY_V 0.96875f
#define THETA   5120.0f
#define POOLW   88.0f

__device__ __forceinline__ void lif_step(float xt, float& u, float& v, int& refc, float& s) {
    u = __fadd_rn(__fmul_rn(u, DECAY_U), __fmul_rn(xt, 64.0f));
    float vn = __fadd_rn(__fmul_rn(v, DECAY_V), u);
    v = refc ? 0.0f : vn;
    s = (v >= THETA) ? 1.0f : 0.0f;
    if (s > 0.f) { refc = 1; v = 0.f; }
    else         { refc = refc > 0 ? refc - 1 : 0; }
}

// Serial LIF over an LDS column: col[t*stride], t=0..127.
__device__ __forceinline__ void lif_seq_lds(float* col, int stride) {
    float u = 0.f, v = 0.f;
    int refc = 0;
    #pragma unroll 16
    for (int t = 0; t < TT; ++t) {
        float s;
        lif_step(col[t * stride], u, v, refc, s);
        col[t * stride] = s;
    }
}

// ---------------- Weight reorder ----------------
// wT1: [ky][kx*2+c][oc16]  800 floats  |  wT2: [tap][c][oc32]  4608 floats
__global__ void wtrans_k(const float* __restrict__ w1, const float* __restrict__ w2,
                         float* __restrict__ wT1, float* __restrict__ wT2) {
    int i = blockIdx.x * 256 + threadIdx.x;
    if (i < 800) {
        int oc = i & 15;
        int r2 = i >> 4;            // ky*10 + (kx*2+c)
        int ky = r2 / 10;
        int rr = r2 - ky * 10;
        int kx = rr >> 1, c = rr & 1;
        wT1[i] = w1[oc*50 + c*25 + ky*5 + kx];
    }
    if (i < 4608) {
        int oc = i & 31;
        int c  = (i >> 5) & 15;
        int tap = i >> 9;
        wT2[i] = w2[oc*144 + c*9 + tap];
    }
}

// ---------------- L1: sum_pool(x,4)*88 + LIF + pack -> pk1 u8 ----------------
__global__ void pool1_lif_k(const float* __restrict__ x, unsigned char* __restrict__ pk1) {
    __shared__ float sb[TT][3];
    int t = threadIdx.x & 127, c = threadIdx.x >> 7;
    int pos = blockIdx.x & 1023, b = blockIdx.x >> 10;
    int px = pos & 31, py = pos >> 5;
    const float* base = x + (size_t)((((b*2 + c)*128 + py*4)*128) + px*4) * 128 + t;
    float s = 0.f;
    #pragma unroll
    for (int dy = 0; dy < 4; ++dy)
        #pragma unroll
        for (int dx = 0; dx < 4; ++dx)
            s += base[(dy*128 + dx) * 128];
    sb[t][c] = s * POOLW;
    __syncthreads();
    if (threadIdx.x < 2) lif_seq_lds(&sb[0][threadIdx.x], 3);
    __syncthreads();
    if (threadIdx.x < 128) {
        unsigned int v = (sb[t][0] > 0.5f ? 1u : 0u) | (sb[t][1] > 0.5f ? 2u : 0u);
        pk1[(size_t)b * 131072 + (size_t)pos * 128 + t] = (unsigned char)v;
    }
}

// ---------------- L2: conv1 single-stage GEMM (2 pos/block) + LIF + pack ----------
// 256 thr: og=tid>>6 (4 oc), pos=(tid>>5)&1, tg=tid&31 (4 t). K=50 staged once.
// Packed v_pk_fma_f32 accumulators (bit-identical to scalar fmaf sequence).
__global__ __launch_bounds__(256) void conv1_gemm_k(const unsigned char* __restrict__ pk1,
                                                    const float* __restrict__ wT1,
                                                    unsigned short* __restrict__ pk2) {
    __shared__ float smem[4760];            // WS[800] | XN[5*6*132=3960] ; sb[128*33=4224] aliases
    float* WS = smem;
    unsigned int* XN = (unsigned int*)(smem + 800);
    float* sb = smem;
    int tid = threadIdx.x;
    int ppair = blockIdx.x & 511, b = blockIdx.x >> 9;
    int py = ppair >> 4, px0 = (ppair & 15) * 2;
    const unsigned char* pp = pk1 + (size_t)b * 131072;

    #pragma unroll
    for (int i = 0; i < 4; ++i) {
        int e = tid + 256*i;
        if (e < 800) WS[e] = wT1[e];
    }
    #pragma unroll
    for (int i = 0; i < 15; ++i) {
        int e = tid + 256*i;                 // 3840 entries
        int row = e >> 7, t = e & 127;
        int ky = row / 6, xc = row - ky*6;
        int iy = py + ky - 2, ix = px0 + xc - 2;
        bool vs = ((unsigned)iy < 32u) && ((unsigned)ix < 32u) && (t > 0);
        XN[row*132 + t] = vs ? (unsigned int)pp[(iy*32 + ix)*128 + t - 1] : 0u;
    }
    __syncthreads();

    int tg = tid & 31;
    int pos = (tid >> 5) & 1;
    int og = tid >> 6;                       // wave-uniform
    v2f acc[4][2];
    #pragma unroll
    for (int i = 0; i < 4; ++i)
        #pragma unroll
        for (int j = 0; j < 2; ++j) acc[i][j] = (v2f){0.f, 0.f};

    #pragma unroll
    for (int ky = 0; ky < 5; ++ky) {
        #pragma unroll
        for (int kx = 0; kx < 5; ++kx) {
            uint4 xw = *(const uint4*)&XN[(ky*6 + kx + pos)*132 + tg*4];
            #pragma unroll
            for (int c = 0; c < 2; ++c) {
                float4 wv = *(const float4*)&WS[(ky*10 + kx*2 + c)*16 + og*4];
                v2f x01 = { (float)((xw.x >> c) & 1u), (float)((xw.y >> c) & 1u) };
                v2f x23 = { (float)((xw.z >> c) & 1u), (float)((xw.w >> c) & 1u) };
                v2f w0 = { wv.x, wv.x }, w1 = { wv.y, wv.y };
                v2f w2 = { wv.z, wv.z }, w3 = { wv.w, wv.w };
                acc[0][0] = __builtin_elementwise_fma(w0, x01, acc[0][0]);
                acc[0][1] = __builtin_elementwise_fma(w0, x23, acc[0][1]);
                acc[1][0] = __builtin_elementwise_fma(w1, x01, acc[1][0]);
                acc[1][1] = __builtin_elementwise_fma(w1, x23, acc[1][1]);
                acc[2][0] = __builtin_elementwise_fma(w2, x01, acc[2][0]);
                acc[2][1] = __builtin_elementwise_fma(w2, x23, acc[2][1]);
                acc[3][0] = __builtin_elementwise_fma(w3, x01, acc[3][0]);
                acc[3][1] = __builtin_elementwise_fma(w3, x23, acc[3][1]);
            }
        }
    }
    __syncthreads();   // XN/WS reads done; reuse smem as sb
    // sb[t][col], col = oc*2 + pos (32 cols, stride 33)
    #pragma unroll
    for (int i = 0; i < 4; ++i)
        #pragma unroll
        for (int j = 0; j < 4; ++j)
            sb[(tg*4 + j)*33 + (og*4 + i)*2 + pos] = acc[i][j >> 1][j & 1];
    __syncthreads();
    if (tid < 32) lif_seq_lds(&sb[tid], 33);
    __syncthreads();
    if (tid < 128) {
        int t = tid;
        #pragma unroll
        for (int p2 = 0; p2 < 2; ++p2) {
            unsigned int w = 0;
            #pragma unroll
            for (int oc = 0; oc < 16; ++oc)
                w |= (sb[t*33 + oc*2 + p2] > 0.5f ? 1u : 0u) << oc;
            int pos_out = py*32 + px0 + p2;
            pk2[(size_t)b * 131072 + (size_t)pos_out * 128 + t] = (unsigned short)w;
        }
    }
}

// ---------------- L3: sum_pool(2)*88 (delayed, packed in) + LIF + pack -> pk3 -----
__global__ __launch_bounds__(256) void pool2pack_k(const unsigned short* __restrict__ pk2,
                                                   unsigned short* __restrict__ pk3) {
    __shared__ float sb[TT][17];
    int tid = threadIdx.x;
    int t = tid & 127, half = tid >> 7;
    int pos = blockIdx.x & 255, b = blockIdx.x >> 8;
    int px = pos & 15, py = pos >> 4;
    unsigned int w0 = 0, w1 = 0, w2 = 0, w3 = 0;
    if (t > 0) {
        const unsigned short* q = pk2 + (size_t)b * 131072 + (size_t)(py*2*32 + px*2) * 128 + (t - 1);
        w0 = q[0]; w1 = q[128]; w2 = q[32*128]; w3 = q[33*128];
    }
    #pragma unroll
    for (int j = 0; j < 8; ++j) {
        int c = half*8 + j;
        int cnt = ((w0 >> c) & 1) + ((w1 >> c) & 1) + ((w2 >> c) & 1) + ((w3 >> c) & 1);
        sb[t][c] = POOLW * (float)cnt;
    }
    __syncthreads();
    if (tid < 16) lif_seq_lds(&sb[0][tid], 17);
    __syncthreads();
    if (tid < 128) {
        unsigned int w = 0;
        #pragma unroll
        for (int c = 0; c < 16; ++c)
            w |= (sb[tid][c] > 0.5f ? 1u : 0u) << c;
        pk3[(size_t)b * 32768 + (size_t)pos * 128 + tid] = (unsigned short)w;
    }
}

// ---------------- L4: conv2 single-stage GEMM + LIF + pack -> pk4 ----------------
// 256 thr: og=tid>>5 (4 oc of 32), tg=tid&31 (4 t). K=144 staged once (packed X).
// Packed v_pk_fma_f32 accumulators.
__global__ __launch_bounds__(256) void conv2_gemm_k(const unsigned short* __restrict__ pk3,
                                                    const float* __restrict__ wT2,
                                                    unsigned int* __restrict__ pk4) {
    __shared__ float smem[5796];            // WS[4608] | XL[9*132=1188] ; sb[128*33] aliases
    float* WS = smem;
    unsigned int* XL = (unsigned int*)(smem + 4608);
    float* sb = smem;
    int tid = threadIdx.x;
    int pos = blockIdx.x & 255, b = blockIdx.x >> 8;
    int px = pos & 15, py = pos >> 4;
    const unsigned short* pp = pk3 + (size_t)b * 32768;

    #pragma unroll
    for (int i = 0; i < 18; ++i)
        WS[tid + 256*i] = wT2[tid + 256*i];
    #pragma unroll
    for (int i = 0; i < 5; ++i) {
        int e = tid + 256*i;
        if (e < 1152) {
            int tap = e >> 7, t = e & 127;
            int ky = tap / 3, kx = tap - ky*3;
            int iy = py + ky - 1, ix = px + kx - 1;
            bool vs = ((unsigned)iy < 16u) && ((unsigned)ix < 16u) && (t > 0);
            XL[tap*132 + t] = vs ? (unsigned int)pp[(iy*16 + ix)*128 + t - 1] : 0u;
        }
    }
    __syncthreads();

    int tg = tid & 31;
    int og = tid >> 5;
    v2f acc[4][2];
    #pragma unroll
    for (int i = 0; i < 4; ++i)
        #pragma unroll
        for (int j = 0; j < 2; ++j) acc[i][j] = (v2f){0.f, 0.f};

    #pragma unroll
    for (int tap = 0; tap < 9; ++tap) {
        uint4 xw = *(const uint4*)&XL[tap*132 + tg*4];
        #pragma unroll
        for (int c = 0; c < 16; ++c) {
            float4 wv = *(const float4*)&WS[tap*512 + c*32 + og*4];
            v2f x01 = { (float)((xw.x >> c) & 1u), (float)((xw.y >> c) & 1u) };
            v2f x23 = { (float)((xw.z >> c) & 1u), (float)((xw.w >> c) & 1u) };
            v2f w0 = { wv.x, wv.x }, w1 = { wv.y, wv.y };
            v2f w2 = { wv.z, wv.z }, w3 = { wv.w, wv.w };
            acc[0][0] = __builtin_elementwise_fma(w0, x01, acc[0][0]);
            acc[0][1] = __builtin_elementwise_fma(w0, x23, acc[0][1]);
            acc[1][0] = __builtin_elementwise_fma(w1, x01, acc[1][0]);
            acc[1][1] = __builtin_elementwise_fma(w1, x23, acc[1][1]);
            acc[2][0] = __builtin_elementwise_fma(w2, x01, acc[2][0]);
            acc[2][1] = __builtin_elementwise_fma(w2, x23, acc[2][1]);
            acc[3][0] = __builtin_elementwise_fma(w3, x01, acc[3][0]);
            acc[3][1] = __builtin_elementwise_fma(w3, x23, acc[3][1]);
        }
    }
    __syncthreads();   // XL/WS reads done; reuse smem as sb
    #pragma unroll
    for (int i = 0; i < 4; ++i)
        #pragma unroll
        for (int j = 0; j < 4; ++j)
            sb[(tg*4 + j)*33 + og*4 + i] = acc[i][j >> 1][j & 1];
    __syncthreads();
    if (tid < 32) lif_seq_lds(&sb[tid], 33);
    __syncthreads();
    if (tid < 128) {
        unsigned int w = 0;
        #pragma unroll
        for (int oc = 0; oc < 32; ++oc)
            w |= (sb[tid*33 + oc] > 0.5f ? 1u : 0u) << oc;
        pk4[(size_t)b * 32768 + (size_t)pos * 128 + tid] = w;
    }
}

// ---------------- L5: sum_pool(2)*88 (delayed, packed in) + LIF -> s5 fp32 --------
__global__ void pool3_lif_k(const unsigned int* __restrict__ pk4, float* __restrict__ s5) {
    __shared__ float sb[TT][3];
    int t = threadIdx.x & 127, pos = threadIdx.x >> 7;
    int n = blockIdx.x * 2 + pos;
    int px = n & 7, py = (n >> 3) & 7, c = (n >> 6) & 31, b = n >> 11;
    float acc = 0.f;
    if (t > 0) {
        const unsigned int* q = pk4 + (size_t)b * 32768 + (size_t)(py*2*16 + px*2) * 128 + (t - 1);
        unsigned int w0 = q[0], w1 = q[128], w2 = q[16*128], w3 = q[17*128];
        int cnt = ((w0 >> c) & 1) + ((w1 >> c) & 1) + ((w2 >> c) & 1) + ((w3 >> c) & 1);
        acc = POOLW * (float)cnt;
    }
    sb[t][pos] = acc;
    __syncthreads();
    if (threadIdx.x < 2) lif_seq_lds(&sb[0][threadIdx.x], 3);
    __syncthreads();
    s5[(size_t)n * TT + t] = sb[t][pos];
}

// ---------------- L6: fc1 tiled K-split GEMM (packed fma) ----------------
__global__ __launch_bounds__(256) void fc1_gemm_k(const float* __restrict__ s5,
                                                  const float* __restrict__ wf1,
                                                  float* __restrict__ part) {
    __shared__ float WT[64][68];
    __shared__ float ST[64][68];
    int bid = blockIdx.x;
    int kc = bid & 7;
    int ot = (bid >> 3) & 7;
    int tt = (bid >> 6) & 1;
    int b  = bid >> 7;
    int tid = threadIdx.x;
    int oo = tid >> 4;
    int to = tid & 15;

    const float* wbase = wf1 + (size_t)(ot*64) * 2048 + kc*256;
    const float* sbase = s5 + (size_t)b * 262144 + (size_t)(kc*256) * 128;

    v2f acc[4][2];
    #pragma unroll
    for (int i = 0; i < 4; ++i)
        #pragma unroll
        for (int j = 0; j < 2; ++j) acc[i][j] = (v2f){0.f, 0.f};

    for (int ks = 0; ks < 4; ++ks) {
        __syncthreads();
        #pragma unroll
        for (int i = 0; i < 16; ++i) {
            int e = tid + 256*i;
            int o = e >> 6, f = e & 63;
            WT[f][o] = wbase[(size_t)o * 2048 + ks*64 + f];
        }
        #pragma unroll
        for (int i = 0; i < 16; ++i) {
            int e = tid + 256*i;
            int f = e >> 6, tl = e & 63;
            int tsrc = tt*64 + tl - 1;
            ST[f][tl] = (tsrc < 0) ? 0.f : sbase[(size_t)f * 128 + ks*64*128 + tsrc];
        }
        __syncthreads();
        #pragma unroll 4
        for (int k = 0; k < 64; ++k) {
            float4 a = *(const float4*)&WT[k][oo*4];
            float4 s = *(const float4*)&ST[k][to*4];
            v2f s01 = { s.x, s.y }, s23 = { s.z, s.w };
            v2f a0 = { a.x, a.x }, a1 = { a.y, a.y };
            v2f a2 = { a.z, a.z }, a3 = { a.w, a.w };
            acc[0][0] = __builtin_elementwise_fma(a0, s01, acc[0][0]);
            acc[0][1] = __builtin_elementwise_fma(a0, s23, acc[0][1]);
            acc[1][0] = __builtin_elementwise_fma(a1, s01, acc[1][0]);
            acc[1][1] = __builtin_elementwise_fma(a1, s23, acc[1][1]);
            acc[2][0] = __builtin_elementwise_fma(a2, s01, acc[2][0]);
            acc[2][1] = __builtin_elementwise_fma(a2, s23, acc[2][1]);
            acc[3][0] = __builtin_elementwise_fma(a3, s01, acc[3][0]);
            acc[3][1] = __builtin_elementwise_fma(a3, s23, acc[3][1]);
        }
    }
    float* pb = part + (size_t)kc * 524288 + (size_t)b * 65536
              + (size_t)(ot*64 + oo*4) * 128 + tt*64 + to*4;
    #pragma unroll
    for (int i = 0; i < 4; ++i)
        #pragma unroll
        for (int j = 0; j < 4; ++j)
            pb[(size_t)i * 128 + j] = acc[i][j >> 1][j & 1];
}

// ---------------- L6b: sum 8 K-chunks (fixed order) + LIF -> s6 ----------------
__global__ void fc1_reduce_lif_k(const float* __restrict__ part, float* __restrict__ s6) {
    __shared__ float sb[TT][3];
    int t = threadIdx.x & 127, pos = threadIdx.x >> 7;
    int n = blockIdx.x * 2 + pos;
    float s = 0.f;
    #pragma unroll
    for (int kc = 0; kc < 8; ++kc)
        s += part[(size_t)kc * 524288 + (size_t)n * 128 + t];
    sb[t][pos] = s;
    __syncthreads();
    if (threadIdx.x < 2) lif_seq_lds(&sb[0][threadIdx.x], 3);
    __syncthreads();
    s6[(size_t)n * TT + t] = sb[t][pos];
}

// ---------------- L7: fc2 512->11 (delayed) + LIF + final shift -> out ----------
__global__ void fc2_lif_k(const float* __restrict__ s6, const float* __restrict__ wf2,
                          float* __restrict__ out) {
    __shared__ float sb[TT];
    int t = threadIdx.x;
    int o = blockIdx.x % 11, b = blockIdx.x / 11;
    float acc = 0.f;
    if (t > 0) {
        const float* sp = s6 + (size_t)b * 65536 + (t - 1);
        const float* wp = wf2 + o * 512;
        for (int f = 0; f < 512; f += 4) {
            float4 w = *(const float4*)&wp[f];
            acc = fmaf(w.x, sp[(size_t)f * 128], acc);
            acc = fmaf(w.y, sp[(size_t)(f+1) * 128], acc);
            acc = fmaf(w.z, sp[(size_t)(f+2) * 128], acc);
            acc = fmaf(w.w, sp[(size_t)(f+3) * 128], acc);
        }
    }
    sb[t] = acc;
    __syncthreads();
    if (t == 0) lif_seq_lds(sb, 1);
    __syncthreads();
    float* q = out + (size_t)(b*11 + o) * TT;
    if (t == 0) q[0] = 0.f;
    if (t < TT - 1) q[t + 1] = sb[t];
}

extern "C" void kernel_launch(void* const* d_in, const int* in_sizes, int n_in,
                              void* d_out, int out_size, void* d_ws, size_t ws_size,
                              hipStream_t stream) {
    const float* x   = (const float*)d_in[0];
    const float* w1  = (const float*)d_in[1];
    const float* w2  = (const float*)d_in[2];
    const float* wf1 = (const float*)d_in[3];
    const float* wf2 = (const float*)d_in[4];
    float* out = (float*)d_out;

    float* ws = (float*)d_ws;
    float* PART = ws;                        // 4,194,304 floats
    float* A    = PART + 4194304;            // 2,097,152 floats (s5)
    float* S6   = A + 2097152;               // 524,288 floats
    float* WT1  = S6 + 524288;               // 800 floats
    float* WT2  = WT1 + 800;                 // 4608 floats
    unsigned char*  PK1 = (unsigned char*)(WT2 + 4608);            // 1,048,576 B
    unsigned short* PK2 = (unsigned short*)(PK1 + 1048576);        // 1,048,576 u16
    unsigned short* PK3 = (unsigned short*)((char*)PK2 + 2097152); // 262,144 u16
    unsigned int*   PK4 = (unsigned int*)((char*)PK3 + 524288);    // 262,144 u32

    // weight reorder for GEMM convs
    wtrans_k<<<dim3(18), 256, 0, stream>>>(w1, w2, WT1, WT2);
    // L1: pool1+LIF+pack -> PK1
    pool1_lif_k<<<dim3(8192), 256, 0, stream>>>(x, PK1);
    // L2: conv1 single-stage GEMM +LIF+pack -> PK2 (2 pos/block, pk-fma)
    conv1_gemm_k<<<dim3(4096), 256, 0, stream>>>(PK1, WT1, PK2);
    // L3: pool2+LIF+pack -> PK3
    pool2pack_k<<<dim3(2048), 256, 0, stream>>>(PK2, PK3);
    // L4: conv2 single-stage GEMM +LIF+pack -> PK4 (pk-fma)
    conv2_gemm_k<<<dim3(2048), 256, 0, stream>>>(PK3, WT2, PK4);
    // L5: pool3+LIF -> A (s5)
    pool3_lif_k<<<dim3(8192), 256, 0, stream>>>(PK4, A);
    // L6: fc1 GEMM -> PART (pk-fma); reduce+LIF -> S6
    fc1_gemm_k      <<<dim3(1024), 256, 0, stream>>>(A, wf1, PART);
    fc1_reduce_lif_k<<<dim3(2048), 256, 0, stream>>>(PART, S6);
    // L7: fc2+LIF+shift -> d_out
    fc2_lif_k<<<dim3(88), 128, 0, stream>>>(S6, wf2, out);
}

// Round 17
// 203.065 us; speedup vs baseline: 1.1349x; 1.0848x over previous
//
#include <hip/hip_runtime.h>

#define TT 128

// LIF constants
#define DECAY_U 0.75f
#define DECAY_V 0.96875f
#define THETA   5120.0f
#define POOLW   88.0f

__device__ __forceinline__ void lif_step(float xt, float& u, float& v, int& refc, float& s) {
    u = __fadd_rn(__fmul_rn(u, DECAY_U), __fmul_rn(xt, 64.0f));
    float vn = __fadd_rn(__fmul_rn(v, DECAY_V), u);
    v = refc ? 0.0f : vn;
    s = (v >= THETA) ? 1.0f : 0.0f;
    if (s > 0.f) { refc = 1; v = 0.f; }
    else         { refc = refc > 0 ? refc - 1 : 0; }
}

// Serial LIF over an LDS column: col[t*stride], t=0..127.
__device__ __forceinline__ void lif_seq_lds(float* col, int stride) {
    float u = 0.f, v = 0.f;
    int refc = 0;
    #pragma unroll 16
    for (int t = 0; t < TT; ++t) {
        float s;
        lif_step(col[t * stride], u, v, refc, s);
        col[t * stride] = s;
    }
}

// ---------------- Weight reorder ----------------
// wT1: [ky][kx*2+c][oc16]  800 floats  |  wT2: [tap][c][oc32]  4608 floats
__global__ void wtrans_k(const float* __restrict__ w1, const float* __restrict__ w2,
                         float* __restrict__ wT1, float* __restrict__ wT2) {
    int i = blockIdx.x * 256 + threadIdx.x;
    if (i < 800) {
        int oc = i & 15;
        int r2 = i >> 4;            // ky*10 + (kx*2+c)
        int ky = r2 / 10;
        int rr = r2 - ky * 10;
        int kx = rr >> 1, c = rr & 1;
        wT1[i] = w1[oc*50 + c*25 + ky*5 + kx];
    }
    if (i < 4608) {
        int oc = i & 31;
        int c  = (i >> 5) & 15;
        int tap = i >> 9;
        wT2[i] = w2[oc*144 + c*9 + tap];
    }
}

// ---------------- L1: sum_pool(x,4)*88 + LIF + pack -> pk1 u8 ----------------
__global__ void pool1_lif_k(const float* __restrict__ x, unsigned char* __restrict__ pk1) {
    __shared__ float sb[TT][3];
    int t = threadIdx.x & 127, c = threadIdx.x >> 7;
    int pos = blockIdx.x & 1023, b = blockIdx.x >> 10;
    int px = pos & 31, py = pos >> 5;
    const float* base = x + (size_t)((((b*2 + c)*128 + py*4)*128) + px*4) * 128 + t;
    float s = 0.f;
    #pragma unroll
    for (int dy = 0; dy < 4; ++dy)
        #pragma unroll
        for (int dx = 0; dx < 4; ++dx)
            s += base[(dy*128 + dx) * 128];
    sb[t][c] = s * POOLW;
    __syncthreads();
    if (threadIdx.x < 2) lif_seq_lds(&sb[0][threadIdx.x], 3);
    __syncthreads();
    if (threadIdx.x < 128) {
        unsigned int v = (sb[t][0] > 0.5f ? 1u : 0u) | (sb[t][1] > 0.5f ? 2u : 0u);
        pk1[(size_t)b * 131072 + (size_t)pos * 128 + t] = (unsigned char)v;
    }
}

// ---------------- L2: conv1 single-stage GEMM (2 pos/block) + LIF + pack ----------
// 256 thr: og=tid>>6 (4 oc), pos=(tid>>5)&1, tg=tid&31 (4 t). K=50 staged once.
__global__ __launch_bounds__(256) void conv1_gemm_k(const unsigned char* __restrict__ pk1,
                                                    const float* __restrict__ wT1,
                                                    unsigned short* __restrict__ pk2) {
    __shared__ float smem[4760];            // WS[800] | XN[5*6*132=3960] ; sb[128*33=4224] aliases
    float* WS = smem;
    unsigned int* XN = (unsigned int*)(smem + 800);
    float* sb = smem;
    int tid = threadIdx.x;
    int ppair = blockIdx.x & 511, b = blockIdx.x >> 9;
    int py = ppair >> 4, px0 = (ppair & 15) * 2;
    const unsigned char* pp = pk1 + (size_t)b * 131072;

    #pragma unroll
    for (int i = 0; i < 4; ++i) {
        int e = tid + 256*i;
        if (e < 800) WS[e] = wT1[e];
    }
    #pragma unroll
    for (int i = 0; i < 15; ++i) {
        int e = tid + 256*i;                 // 3840 entries
        int row = e >> 7, t = e & 127;
        int ky = row / 6, xc = row - ky*6;
        int iy = py + ky - 2, ix = px0 + xc - 2;
        bool vs = ((unsigned)iy < 32u) && ((unsigned)ix < 32u) && (t > 0);
        XN[row*132 + t] = vs ? (unsigned int)pp[(iy*32 + ix)*128 + t - 1] : 0u;
    }
    __syncthreads();

    int tg = tid & 31;
    int pos = (tid >> 5) & 1;
    int og = tid >> 6;                       // wave-uniform
    float acc[4][4];
    #pragma unroll
    for (int i = 0; i < 4; ++i)
        #pragma unroll
        for (int j = 0; j < 4; ++j) acc[i][j] = 0.f;

    #pragma unroll
    for (int ky = 0; ky < 5; ++ky) {
        #pragma unroll
        for (int kx = 0; kx < 5; ++kx) {
            uint4 xw = *(const uint4*)&XN[(ky*6 + kx + pos)*132 + tg*4];
            #pragma unroll
            for (int c = 0; c < 2; ++c) {
                float4 wv = *(const float4*)&WS[(ky*10 + kx*2 + c)*16 + og*4];
                float x0 = (float)((xw.x >> c) & 1u);
                float x1 = (float)((xw.y >> c) & 1u);
                float x2 = (float)((xw.z >> c) & 1u);
                float x3 = (float)((xw.w >> c) & 1u);
                acc[0][0] = fmaf(wv.x, x0, acc[0][0]);
                acc[0][1] = fmaf(wv.x, x1, acc[0][1]);
                acc[0][2] = fmaf(wv.x, x2, acc[0][2]);
                acc[0][3] = fmaf(wv.x, x3, acc[0][3]);
                acc[1][0] = fmaf(wv.y, x0, acc[1][0]);
                acc[1][1] = fmaf(wv.y, x1, acc[1][1]);
                acc[1][2] = fmaf(wv.y, x2, acc[1][2]);
                acc[1][3] = fmaf(wv.y, x3, acc[1][3]);
                acc[2][0] = fmaf(wv.z, x0, acc[2][0]);
                acc[2][1] = fmaf(wv.z, x1, acc[2][1]);
                acc[2][2] = fmaf(wv.z, x2, acc[2][2]);
                acc[2][3] = fmaf(wv.z, x3, acc[2][3]);
                acc[3][0] = fmaf(wv.w, x0, acc[3][0]);
                acc[3][1] = fmaf(wv.w, x1, acc[3][1]);
                acc[3][2] = fmaf(wv.w, x2, acc[3][2]);
                acc[3][3] = fmaf(wv.w, x3, acc[3][3]);
            }
        }
    }
    __syncthreads();   // XN/WS reads done; reuse smem as sb
    // sb[t][col], col = oc*2 + pos (32 cols, stride 33)
    #pragma unroll
    for (int i = 0; i < 4; ++i)
        #pragma unroll
        for (int j = 0; j < 4; ++j)
            sb[(tg*4 + j)*33 + (og*4 + i)*2 + pos] = acc[i][j];
    __syncthreads();
    if (tid < 32) lif_seq_lds(&sb[tid], 33);
    __syncthreads();
    if (tid < 128) {
        int t = tid;
        #pragma unroll
        for (int p2 = 0; p2 < 2; ++p2) {
            unsigned int w = 0;
            #pragma unroll
            for (int oc = 0; oc < 16; ++oc)
                w |= (sb[t*33 + oc*2 + p2] > 0.5f ? 1u : 0u) << oc;
            int pos_out = py*32 + px0 + p2;
            pk2[(size_t)b * 131072 + (size_t)pos_out * 128 + t] = (unsigned short)w;
        }
    }
}

// ---------------- L3: sum_pool(2)*88 (delayed, packed in) + LIF + pack -> pk3 -----
__global__ __launch_bounds__(256) void pool2pack_k(const unsigned short* __restrict__ pk2,
                                                   unsigned short* __restrict__ pk3) {
    __shared__ float sb[TT][17];
    int tid = threadIdx.x;
    int t = tid & 127, half = tid >> 7;
    int pos = blockIdx.x & 255, b = blockIdx.x >> 8;
    int px = pos & 15, py = pos >> 4;
    unsigned int w0 = 0, w1 = 0, w2 = 0, w3 = 0;
    if (t > 0) {
        const unsigned short* q = pk2 + (size_t)b * 131072 + (size_t)(py*2*32 + px*2) * 128 + (t - 1);
        w0 = q[0]; w1 = q[128]; w2 = q[32*128]; w3 = q[33*128];
    }
    #pragma unroll
    for (int j = 0; j < 8; ++j) {
        int c = half*8 + j;
        int cnt = ((w0 >> c) & 1) + ((w1 >> c) & 1) + ((w2 >> c) & 1) + ((w3 >> c) & 1);
        sb[t][c] = POOLW * (float)cnt;
    }
    __syncthreads();
    if (tid < 16) lif_seq_lds(&sb[0][tid], 17);
    __syncthreads();
    if (tid < 128) {
        unsigned int w = 0;
        #pragma unroll
        for (int c = 0; c < 16; ++c)
            w |= (sb[tid][c] > 0.5f ? 1u : 0u) << c;
        pk3[(size_t)b * 32768 + (size_t)pos * 128 + tid] = (unsigned short)w;
    }
}

// ---------------- L4: conv2 single-stage GEMM (2 pos/block, 8oc x 4t) + LIF + pack -
// 256 thr: pe=tid>>7 (position), og=(tid>>5)&3 (8 oc), tg=tid&31 (4 t).
// Extract/cvt amortized over 8 oc. FMA order per output (tap->c) identical to r11.
__global__ __launch_bounds__(256) void conv2_gemm_k(const unsigned short* __restrict__ pk3,
                                                    const float* __restrict__ wT2,
                                                    unsigned int* __restrict__ pk4) {
    __shared__ float smem[8448];            // WS[4608] | XL[2][1188]u ; sb[2][128*33] aliases
    float* WS = smem;
    unsigned int* XL = (unsigned int*)(smem + 4608);
    float* sb = smem;
    int tid = threadIdx.x;
    int pp2 = blockIdx.x & 127, b = blockIdx.x >> 7;   // pair of positions
    const unsigned short* pp = pk3 + (size_t)b * 32768;

    #pragma unroll
    for (int i = 0; i < 18; ++i)
        WS[tid + 256*i] = wT2[tid + 256*i];
    #pragma unroll
    for (int i = 0; i < 9; ++i) {
        int e = tid + 256*i;                 // 0..2303
        int pe2 = e >= 1152 ? 1 : 0;
        int r = e - pe2*1152;
        int tap = r >> 7, t = r & 127;
        int pos_l = pp2*2 + pe2;
        int px = pos_l & 15, py = pos_l >> 4;
        int ky = tap / 3, kx = tap - ky*3;
        int iy = py + ky - 1, ix = px + kx - 1;
        bool vs = ((unsigned)iy < 16u) && ((unsigned)ix < 16u) && (t > 0);
        XL[pe2*1188 + tap*132 + t] = vs ? (unsigned int)pp[(iy*16 + ix)*128 + t - 1] : 0u;
    }
    __syncthreads();

    int tg = tid & 31;
    int og = (tid >> 5) & 3;
    int pe = tid >> 7;
    const unsigned int* XLp = XL + pe*1188;
    float acc[8][4];
    #pragma unroll
    for (int i = 0; i < 8; ++i)
        #pragma unroll
        for (int j = 0; j < 4; ++j) acc[i][j] = 0.f;

    #pragma unroll
    for (int tap = 0; tap < 9; ++tap) {
        uint4 xw = *(const uint4*)&XLp[tap*132 + tg*4];
        #pragma unroll
        for (int c = 0; c < 16; ++c) {
            float4 wv0 = *(const float4*)&WS[tap*512 + c*32 + og*8];
            float4 wv1 = *(const float4*)&WS[tap*512 + c*32 + og*8 + 4];
            float x0 = (float)((xw.x >> c) & 1u);
            float x1 = (float)((xw.y >> c) & 1u);
            float x2 = (float)((xw.z >> c) & 1u);
            float x3 = (float)((xw.w >> c) & 1u);
            acc[0][0] = fmaf(wv0.x, x0, acc[0][0]);
            acc[0][1] = fmaf(wv0.x, x1, acc[0][1]);
            acc[0][2] = fmaf(wv0.x, x2, acc[0][2]);
            acc[0][3] = fmaf(wv0.x, x3, acc[0][3]);
            acc[1][0] = fmaf(wv0.y, x0, acc[1][0]);
            acc[1][1] = fmaf(wv0.y, x1, acc[1][1]);
            acc[1][2] = fmaf(wv0.y, x2, acc[1][2]);
            acc[1][3] = fmaf(wv0.y, x3, acc[1][3]);
            acc[2][0] = fmaf(wv0.z, x0, acc[2][0]);
            acc[2][1] = fmaf(wv0.z, x1, acc[2][1]);
            acc[2][2] = fmaf(wv0.z, x2, acc[2][2]);
            acc[2][3] = fmaf(wv0.z, x3, acc[2][3]);
            acc[3][0] = fmaf(wv0.w, x0, acc[3][0]);
            acc[3][1] = fmaf(wv0.w, x1, acc[3][1]);
            acc[3][2] = fmaf(wv0.w, x2, acc[3][2]);
            acc[3][3] = fmaf(wv0.w, x3, acc[3][3]);
            acc[4][0] = fmaf(wv1.x, x0, acc[4][0]);
            acc[4][1] = fmaf(wv1.x, x1, acc[4][1]);
            acc[4][2] = fmaf(wv1.x, x2, acc[4][2]);
            acc[4][3] = fmaf(wv1.x, x3, acc[4][3]);
            acc[5][0] = fmaf(wv1.y, x0, acc[5][0]);
            acc[5][1] = fmaf(wv1.y, x1, acc[5][1]);
            acc[5][2] = fmaf(wv1.y, x2, acc[5][2]);
            acc[5][3] = fmaf(wv1.y, x3, acc[5][3]);
            acc[6][0] = fmaf(wv1.z, x0, acc[6][0]);
            acc[6][1] = fmaf(wv1.z, x1, acc[6][1]);
            acc[6][2] = fmaf(wv1.z, x2, acc[6][2]);
            acc[6][3] = fmaf(wv1.z, x3, acc[6][3]);
            acc[7][0] = fmaf(wv1.w, x0, acc[7][0]);
            acc[7][1] = fmaf(wv1.w, x1, acc[7][1]);
            acc[7][2] = fmaf(wv1.w, x2, acc[7][2]);
            acc[7][3] = fmaf(wv1.w, x3, acc[7][3]);
        }
    }
    __syncthreads();   // XL/WS reads done; reuse smem as two r11-style sb regions
    float* sbp = sb + pe*4224;
    #pragma unroll
    for (int i = 0; i < 8; ++i)
        #pragma unroll
        for (int j = 0; j < 4; ++j)
            sbp[(tg*4 + j)*33 + og*8 + i] = acc[i][j];
    __syncthreads();
    if (tid < 64) {
        int pe_l = tid >> 5, oc_l = tid & 31;
        lif_seq_lds(&sb[pe_l*4224 + oc_l], 33);
    }
    __syncthreads();
    {
        int t = tid & 127, pe_l = tid >> 7;
        unsigned int w = 0;
        #pragma unroll
        for (int oc = 0; oc < 32; ++oc)
            w |= (sb[pe_l*4224 + t*33 + oc] > 0.5f ? 1u : 0u) << oc;
        pk4[(size_t)b * 32768 + (size_t)(pp2*2 + pe_l) * 128 + t] = w;
    }
}

// ---------------- L5: sum_pool(2)*88 (delayed, packed in) + LIF -> s5 fp32 --------
__global__ void pool3_lif_k(const unsigned int* __restrict__ pk4, float* __restrict__ s5) {
    __shared__ float sb[TT][3];
    int t = threadIdx.x & 127, pos = threadIdx.x >> 7;
    int n = blockIdx.x * 2 + pos;
    int px = n & 7, py = (n >> 3) & 7, c = (n >> 6) & 31, b = n >> 11;
    float acc = 0.f;
    if (t > 0) {
        const unsigned int* q = pk4 + (size_t)b * 32768 + (size_t)(py*2*16 + px*2) * 128 + (t - 1);
        unsigned int w0 = q[0], w1 = q[128], w2 = q[16*128], w3 = q[17*128];
        int cnt = ((w0 >> c) & 1) + ((w1 >> c) & 1) + ((w2 >> c) & 1) + ((w3 >> c) & 1);
        acc = POOLW * (float)cnt;
    }
    sb[t][pos] = acc;
    __syncthreads();
    if (threadIdx.x < 2) lif_seq_lds(&sb[0][threadIdx.x], 3);
    __syncthreads();
    s5[(size_t)n * TT + t] = sb[t][pos];
}

// ---------------- L6: fc1 tiled K-split GEMM ----------------
__global__ __launch_bounds__(256) void fc1_gemm_k(const float* __restrict__ s5,
                                                  const float* __restrict__ wf1,
                                                  float* __restrict__ part) {
    __shared__ float WT[64][68];
    __shared__ float ST[64][68];
    int bid = blockIdx.x;
    int kc = bid & 7;
    int ot = (bid >> 3) & 7;
    int tt = (bid >> 6) & 1;
    int b  = bid >> 7;
    int tid = threadIdx.x;
    int oo = tid >> 4;
    int to = tid & 15;

    const float* wbase = wf1 + (size_t)(ot*64) * 2048 + kc*256;
    const float* sbase = s5 + (size_t)b * 262144 + (size_t)(kc*256) * 128;

    float acc[4][4];
    #pragma unroll
    for (int i = 0; i < 4; ++i)
        #pragma unroll
        for (int j = 0; j < 4; ++j) acc[i][j] = 0.f;

    for (int ks = 0; ks < 4; ++ks) {
        __syncthreads();
        #pragma unroll
        for (int i = 0; i < 16; ++i) {
            int e = tid + 256*i;
            int o = e >> 6, f = e & 63;
            WT[f][o] = wbase[(size_t)o * 2048 + ks*64 + f];
        }
        #pragma unroll
        for (int i = 0; i < 16; ++i) {
            int e = tid + 256*i;
            int f = e >> 6, tl = e & 63;
            int tsrc = tt*64 + tl - 1;
            ST[f][tl] = (tsrc < 0) ? 0.f : sbase[(size_t)f * 128 + ks*64*128 + tsrc];
        }
        __syncthreads();
        #pragma unroll 4
        for (int k = 0; k < 64; ++k) {
            float4 a = *(const float4*)&WT[k][oo*4];
            float4 s = *(const float4*)&ST[k][to*4];
            acc[0][0] = fmaf(a.x, s.x, acc[0][0]);
            acc[0][1] = fmaf(a.x, s.y, acc[0][1]);
            acc[0][2] = fmaf(a.x, s.z, acc[0][2]);
            acc[0][3] = fmaf(a.x, s.w, acc[0][3]);
            acc[1][0] = fmaf(a.y, s.x, acc[1][0]);
            acc[1][1] = fmaf(a.y, s.y, acc[1][1]);
            acc[1][2] = fmaf(a.y, s.z, acc[1][2]);
            acc[1][3] = fmaf(a.y, s.w, acc[1][3]);
            acc[2][0] = fmaf(a.z, s.x, acc[2][0]);
            acc[2][1] = fmaf(a.z, s.y, acc[2][1]);
            acc[2][2] = fmaf(a.z, s.z, acc[2][2]);
            acc[2][3] = fmaf(a.z, s.w, acc[2][3]);
            acc[3][0] = fmaf(a.w, s.x, acc[3][0]);
            acc[3][1] = fmaf(a.w, s.y, acc[3][1]);
            acc[3][2] = fmaf(a.w, s.z, acc[3][2]);
            acc[3][3] = fmaf(a.w, s.w, acc[3][3]);
        }
    }
    float* pb = part + (size_t)kc * 524288 + (size_t)b * 65536
              + (size_t)(ot*64 + oo*4) * 128 + tt*64 + to*4;
    #pragma unroll
    for (int i = 0; i < 4; ++i)
        #pragma unroll
        for (int j = 0; j < 4; ++j)
            pb[(size_t)i * 128 + j] = acc[i][j];
}

// ---------------- L6b: sum 8 K-chunks (fixed order) + LIF -> s6 ----------------
__global__ void fc1_reduce_lif_k(const float* __restrict__ part, float* __restrict__ s6) {
    __shared__ float sb[TT][3];
    int t = threadIdx.x & 127, pos = threadIdx.x >> 7;
    int n = blockIdx.x * 2 + pos;
    float s = 0.f;
    #pragma unroll
    for (int kc = 0; kc < 8; ++kc)
        s += part[(size_t)kc * 524288 + (size_t)n * 128 + t];
    sb[t][pos] = s;
    __syncthreads();
    if (threadIdx.x < 2) lif_seq_lds(&sb[0][threadIdx.x], 3);
    __syncthreads();
    s6[(size_t)n * TT + t] = sb[t][pos];
}

// ---------------- L7: fc2 512->11 (delayed) + LIF + final shift -> out ----------
__global__ void fc2_lif_k(const float* __restrict__ s6, const float* __restrict__ wf2,
                          float* __restrict__ out) {
    __shared__ float sb[TT];
    int t = threadIdx.x;
    int o = blockIdx.x % 11, b = blockIdx.x / 11;
    float acc = 0.f;
    if (t > 0) {
        const float* sp = s6 + (size_t)b * 65536 + (t - 1);
        const float* wp = wf2 + o * 512;
        for (int f = 0; f < 512; f += 4) {
            float4 w = *(const float4*)&wp[f];
            acc = fmaf(w.x, sp[(size_t)f * 128], acc);
            acc = fmaf(w.y, sp[(size_t)(f+1) * 128], acc);
            acc = fmaf(w.z, sp[(size_t)(f+2) * 128], acc);
            acc = fmaf(w.w, sp[(size_t)(f+3) * 128], acc);
        }
    }
    sb[t] = acc;
    __syncthreads();
    if (t == 0) lif_seq_lds(sb, 1);
    __syncthreads();
    float* q = out + (size_t)(b*11 + o) * TT;
    if (t == 0) q[0] = 0.f;
    if (t < TT - 1) q[t + 1] = sb[t];
}

extern "C" void kernel_launch(void* const* d_in, const int* in_sizes, int n_in,
                              void* d_out, int out_size, void* d_ws, size_t ws_size,
                              hipStream_t stream) {
    const float* x   = (const float*)d_in[0];
    const float* w1  = (const float*)d_in[1];
    const float* w2  = (const float*)d_in[2];
    const float* wf1 = (const float*)d_in[3];
    const float* wf2 = (const float*)d_in[4];
    float* out = (float*)d_out;

    float* ws = (float*)d_ws;
    float* PART = ws;                        // 4,194,304 floats
    float* A    = PART + 4194304;            // 2,097,152 floats (s5)
    float* S6   = A + 2097152;               // 524,288 floats
    float* WT1  = S6 + 524288;               // 800 floats
    float* WT2  = WT1 + 800;                 // 4608 floats
    unsigned char*  PK1 = (unsigned char*)(WT2 + 4608);            // 1,048,576 B
    unsigned short* PK2 = (unsigned short*)(PK1 + 1048576);        // 1,048,576 u16
    unsigned short* PK3 = (unsigned short*)((char*)PK2 + 2097152); // 262,144 u16
    unsigned int*   PK4 = (unsigned int*)((char*)PK3 + 524288);    // 262,144 u32

    // weight reorder for GEMM convs
    wtrans_k<<<dim3(18), 256, 0, stream>>>(w1, w2, WT1, WT2);
    // L1: pool1+LIF+pack -> PK1
    pool1_lif_k<<<dim3(8192), 256, 0, stream>>>(x, PK1);
    // L2: conv1 single-stage GEMM +LIF+pack -> PK2 (2 pos/block)
    conv1_gemm_k<<<dim3(4096), 256, 0, stream>>>(PK1, WT1, PK2);
    // L3: pool2+LIF+pack -> PK3
    pool2pack_k<<<dim3(2048), 256, 0, stream>>>(PK2, PK3);
    // L4: conv2 single-stage GEMM +LIF+pack -> PK4 (2 pos/block, 8oc x 4t)
    conv2_gemm_k<<<dim3(1024), 256, 0, stream>>>(PK3, WT2, PK4);
    // L5: pool3+LIF -> A (s5)
    pool3_lif_k<<<dim3(8192), 256, 0, stream>>>(PK4, A);
    // L6: fc1 GEMM -> PART; reduce+LIF -> S6
    fc1_gemm_k      <<<dim3(1024), 256, 0, stream>>>(A, wf1, PART);
    fc1_reduce_lif_k<<<dim3(2048), 256, 0, stream>>>(PART, S6);
    // L7: fc2+LIF+shift -> d_out
    fc2_lif_k<<<dim3(88), 128, 0, stream>>>(S6, wf2, out);
}